// Round 2
// baseline (668.196 us; speedup 1.0000x reference)
//
#include <hip/hip_runtime.h>

// LIF constants folded:
//   i' = 0.8*s + x
//   v' = 0.9*m + 0.1*i'
//   spike = v' >= 1.0
// Then 2x2 max-pool of the {0,1} spike map.
//
// R2: 2x vertical unroll per thread. 12 independent float4 loads in flight
// (~48 data VGPRs) to fix the VGPR=16 load-serialization seen in R1.

constexpr int B = 16, C = 64, H = 256, W = 256;
constexpr int W4  = W / 4;               // 64 float4 groups per input row
constexpr int OW2 = (W / 2) / 2;         // 64 float2 groups per output row
constexpr int OROWS = B * C * (H / 2);   // 131072 output rows
constexpr int NTHREADS = (OROWS / 2) * W4; // thread = 2 output rows x 1 float4 group

__device__ __forceinline__ float lif_v(float m, float s, float x) {
    return fmaf(0.9f, m, 0.1f * fmaf(0.8f, s, x));
}

// pooled float2 from two input rows' float4s (4 cols -> 2 pooled outputs)
__device__ __forceinline__ float2 pool2(const float4& Ma, const float4& Sa, const float4& Xa,
                                        const float4& Mb, const float4& Sb, const float4& Xb) {
    float a0 = lif_v(Ma.x, Sa.x, Xa.x), a1 = lif_v(Ma.y, Sa.y, Xa.y);
    float a2 = lif_v(Ma.z, Sa.z, Xa.z), a3 = lif_v(Ma.w, Sa.w, Xa.w);
    float b0 = lif_v(Mb.x, Sb.x, Xb.x), b1 = lif_v(Mb.y, Sb.y, Xb.y);
    float b2 = lif_v(Mb.z, Sb.z, Xb.z), b3 = lif_v(Mb.w, Sb.w, Xb.w);
    float w0 = fmaxf(fmaxf(a0, a1), fmaxf(b0, b1));
    float w1 = fmaxf(fmaxf(a2, a3), fmaxf(b2, b3));
    float2 o;
    o.x = (w0 >= 1.0f) ? 1.0f : 0.0f;
    o.y = (w1 >= 1.0f) ? 1.0f : 0.0f;
    return o;
}

__global__ __launch_bounds__(256) void lif_pool_kernel(
    const float4* __restrict__ x,
    const float4* __restrict__ m,
    const float4* __restrict__ s,
    float2* __restrict__ out)
{
    int t = blockIdx.x * blockDim.x + threadIdx.x;
    int g  = t & 63;         // float4 column group (wave-contiguous -> 1KB coalesced)
    int rp = t >> 6;         // row-pair-pair index: covers output rows 2rp, 2rp+1

    int ib = rp * 4 * W4 + g;  // float4 index of input row 4*rp, group g

    // Issue all 12 loads before any use — maximize loads in flight.
    float4 X0 = x[ib], X1 = x[ib + W4], X2 = x[ib + 2 * W4], X3 = x[ib + 3 * W4];
    float4 M0 = m[ib], M1 = m[ib + W4], M2 = m[ib + 2 * W4], M3 = m[ib + 3 * W4];
    float4 S0 = s[ib], S1 = s[ib + W4], S2 = s[ib + 2 * W4], S3 = s[ib + 3 * W4];

    float2 o0 = pool2(M0, S0, X0, M1, S1, X1);
    float2 o1 = pool2(M2, S2, X2, M3, S3, X3);

    int ob = rp * 2 * OW2 + g;
    out[ob] = o0;
    out[ob + OW2] = o1;
}

extern "C" void kernel_launch(void* const* d_in, const int* in_sizes, int n_in,
                              void* d_out, int out_size, void* d_ws, size_t ws_size,
                              hipStream_t stream) {
    const float4* x = (const float4*)d_in[0];  // input_signal
    const float4* m = (const float4*)d_in[1];  // membrane
    const float4* s = (const float4*)d_in[2];  // synaptic
    float2* out = (float2*)d_out;

    constexpr int BLOCK = 256;
    constexpr int GRID = NTHREADS / BLOCK;  // 16384, exact fit
    lif_pool_kernel<<<GRID, BLOCK, 0, stream>>>(x, m, s, out);
}